// Round 2
// baseline (907.530 us; speedup 1.0000x reference)
//
#include <hip/hip_runtime.h>
#include <hip/hip_bf16.h>
#include <math.h>

// ---------------- constants ----------------
#define BB 8192
#define DD 1024
#define HH 4096
#define EE 4
#define NT 132              // row tiles of 128 covering B*k + per-expert pad
#define CAP (NT * 128)      // 16896 packed-row capacity

typedef __attribute__((ext_vector_type(8))) __bf16 bf16x8;
typedef __attribute__((ext_vector_type(4))) float f32x4;

__device__ __forceinline__ unsigned short f2bf(float f) {
    union { float f; unsigned u; } c; c.f = f;
    unsigned u = c.u;
    unsigned r = (u + 0x7FFFu + ((u >> 16) & 1u)) >> 16;
    return (unsigned short)r;
}

__device__ __forceinline__ void load_lds16(const void* g, void* l) {
    __builtin_amdgcn_global_load_lds(
        (const __attribute__((address_space(1))) void*)g,
        (__attribute__((address_space(3))) void*)l, 16, 0, 0);
}

// ---------------- weight transpose + bf16 convert ----------------
// src fp32 [E][R][C]  ->  dst bf16 [E][C][R]
template <int R, int C>
__global__ void k_prep(const float* __restrict__ src, unsigned short* __restrict__ dst) {
    __shared__ unsigned short tileT[64 * 72];   // [c][r], pad 72
    const int e = blockIdx.z;
    const int r0 = blockIdx.y * 64, c0 = blockIdx.x * 64;
    const float* s = src + (size_t)e * R * C;
    unsigned short* d = dst + (size_t)e * R * C;
    const int tid = threadIdx.x;
    const int cc = (tid & 15) * 4;
#pragma unroll
    for (int it = 0; it < 4; ++it) {
        int rr = (tid >> 4) + it * 16;
        float4 v = *(const float4*)(s + (size_t)(r0 + rr) * C + c0 + cc);
        tileT[(cc + 0) * 72 + rr] = f2bf(v.x);
        tileT[(cc + 1) * 72 + rr] = f2bf(v.y);
        tileT[(cc + 2) * 72 + rr] = f2bf(v.z);
        tileT[(cc + 3) * 72 + rr] = f2bf(v.w);
    }
    __syncthreads();
#pragma unroll
    for (int it = 0; it < 2; ++it) {
        int chunk = tid + it * 256;
        int cl = chunk >> 3, rl = (chunk & 7) * 8;
        uint4 vv = *(const uint4*)&tileT[cl * 72 + rl];
        *(uint4*)(d + (size_t)(c0 + cl) * R + r0 + rl) = vv;
    }
}

// ---------------- gating: logits, softmax, top2, LN stats, routing ----------------
__global__ void k_gate(const float* __restrict__ x, const float* __restrict__ gw,
                       const float* __restrict__ gb,
                       float* __restrict__ mu, float* __restrict__ rstd,
                       int* __restrict__ cnt, int* __restrict__ rows_tmp,
                       float* __restrict__ wts_tmp,
                       float* __restrict__ probs_out, float* __restrict__ idx_out,
                       float* __restrict__ w_out) {
    const int r = blockIdx.x, tid = threadIdx.x;
    float4 xv = *(const float4*)(x + (size_t)r * DD + tid * 4);
    float l[4], s, ss;
    s = xv.x + xv.y + xv.z + xv.w;
    ss = xv.x * xv.x + xv.y * xv.y + xv.z * xv.z + xv.w * xv.w;
#pragma unroll
    for (int e = 0; e < 4; ++e) {
        float4 g = *(const float4*)(gw + (size_t)e * DD + tid * 4);
        l[e] = xv.x * g.x + xv.y * g.y + xv.z * g.z + xv.w * g.w;
    }
    __shared__ float red[6][256];
    red[0][tid] = l[0]; red[1][tid] = l[1]; red[2][tid] = l[2]; red[3][tid] = l[3];
    red[4][tid] = s; red[5][tid] = ss;
    __syncthreads();
    for (int off = 128; off > 0; off >>= 1) {
        if (tid < off) {
#pragma unroll
            for (int q = 0; q < 6; ++q) red[q][tid] += red[q][tid + off];
        }
        __syncthreads();
    }
    if (tid == 0) {
        float sum = red[4][0], sumsq = red[5][0];
        float m = sum * (1.0f / DD);
        float var = sumsq * (1.0f / DD) - m * m;
        mu[r] = m;
        rstd[r] = rsqrtf(var + 1e-5f);
        float lg[4];
#pragma unroll
        for (int e = 0; e < 4; ++e) lg[e] = red[e][0] + gb[e];
        float mx = fmaxf(fmaxf(lg[0], lg[1]), fmaxf(lg[2], lg[3]));
        float p[4], tot = 0.f;
#pragma unroll
        for (int e = 0; e < 4; ++e) { p[e] = expf(lg[e] - mx); tot += p[e]; }
        float inv = 1.0f / tot;
#pragma unroll
        for (int e = 0; e < 4; ++e) { p[e] *= inv; probs_out[(size_t)r * 4 + e] = p[e]; }
        int e0 = 0; float p0 = p[0];
#pragma unroll
        for (int e = 1; e < 4; ++e) if (p[e] > p0) { p0 = p[e]; e0 = e; }
        int e1 = -1; float p1 = -1.f;
#pragma unroll
        for (int e = 0; e < 4; ++e) if (e != e0 && p[e] > p1) { p1 = p[e]; e1 = e; }
        float s2 = 1.0f / (p0 + p1 + 1e-9f);
        float w0 = p0 * s2, w1v = p1 * s2;
        idx_out[r * 2 + 0] = (float)e0;
        idx_out[r * 2 + 1] = (float)e1;
        w_out[r * 2 + 0] = w0;
        w_out[r * 2 + 1] = w1v;
        int pos0 = atomicAdd(cnt + e0, 1);
        rows_tmp[e0 * BB + pos0] = r; wts_tmp[e0 * BB + pos0] = w0;
        int pos1 = atomicAdd(cnt + e1, 1);
        rows_tmp[e1 * BB + pos1] = r; wts_tmp[e1 * BB + pos1] = w1v;
    }
}

// ---------------- aux loss + aligned offsets + tile table ----------------
__global__ void k_aux(const float* __restrict__ probs, const int* __restrict__ cnt,
                      int* __restrict__ aoff, int* __restrict__ tile_e,
                      float* __restrict__ aux_out) {
    const int tid = threadIdx.x;
    float s0 = 0, s1 = 0, s2 = 0, s3 = 0;
    for (int r = tid; r < BB; r += 256) {
        float4 p = *(const float4*)(probs + (size_t)r * 4);
        s0 += p.x; s1 += p.y; s2 += p.z; s3 += p.w;
    }
    __shared__ float red[4][256];
    red[0][tid] = s0; red[1][tid] = s1; red[2][tid] = s2; red[3][tid] = s3;
    __syncthreads();
    for (int off = 128; off > 0; off >>= 1) {
        if (tid < off) {
#pragma unroll
            for (int q = 0; q < 4; ++q) red[q][tid] += red[q][tid + off];
        }
        __syncthreads();
    }
    if (tid == 0) {
        float aux = 0.f;
        for (int e = 0; e < 4; ++e) {
            float mean_p = red[e][0] * (1.0f / BB);
            float frac = (float)cnt[e] * (1.0f / (BB * 2));
            aux += frac * mean_p;
        }
        aux_out[0] = 4.0f * aux;
        int a = 0; aoff[0] = 0;
        for (int e = 0; e < 4; ++e) { a += ((cnt[e] + 127) >> 7) << 7; aoff[e + 1] = a; }
        for (int t = 0; t < NT; ++t) {
            int ee = 0;
            for (int e = 0; e < 4; ++e)
                if (t * 128 >= aoff[e] && t * 128 < aoff[e + 1]) ee = e;
            tile_e[t] = ee;
        }
    }
}

// ---------------- pack: gather rows, LN + per-expert affine, bf16 ----------------
__global__ void k_pack(const float* __restrict__ x, const float* __restrict__ lnw,
                       const float* __restrict__ lnb,
                       const float* __restrict__ mu, const float* __restrict__ rstd,
                       const int* __restrict__ cnt, const int* __restrict__ aoff,
                       const int* __restrict__ tile_e,
                       const int* __restrict__ rows_tmp, const float* __restrict__ wts_tmp,
                       int* __restrict__ row_pk, float* __restrict__ wt_pk,
                       unsigned short* __restrict__ Apk) {
    const int i = blockIdx.x;
    if (i >= aoff[4]) return;
    const int e = tile_e[i >> 7];
    const int j = i - aoff[e];
    const int tid = threadIdx.x;
    unsigned short* dst = Apk + (size_t)i * DD + tid * 4;
    if (j < cnt[e]) {
        int b = rows_tmp[e * BB + j];
        if (tid == 0) { row_pk[i] = b; wt_pk[i] = wts_tmp[e * BB + j]; }
        float m = mu[b], rs = rstd[b];
        float4 xv = *(const float4*)(x + (size_t)b * DD + tid * 4);
        float4 wv = *(const float4*)(lnw + (size_t)e * DD + tid * 4);
        float4 bv = *(const float4*)(lnb + (size_t)e * DD + tid * 4);
        ushort4 o;
        o.x = f2bf((xv.x - m) * rs * wv.x + bv.x);
        o.y = f2bf((xv.y - m) * rs * wv.y + bv.y);
        o.z = f2bf((xv.z - m) * rs * wv.z + bv.z);
        o.w = f2bf((xv.w - m) * rs * wv.w + bv.w);
        *(ushort4*)dst = o;
    } else {
        if (tid == 0) { row_pk[i] = -1; wt_pk[i] = 0.f; }
        ushort4 z; z.x = z.y = z.z = z.w = 0;
        *(ushort4*)dst = z;
    }
}

// ---------------- grouped GEMM (m97 recipe) ----------------
// MODE 1: H = gelu(A @ W^T + b1) -> bf16 Hout     (K=1024, N=4096)
// MODE 2: y[row] += wt * (A @ W^T + b2)           (K=4096, N=1024)
template <int K, int N, int MODE>
__global__ void moe_gemm(const __bf16* __restrict__ A, const __bf16* __restrict__ W,
                         const float* __restrict__ bias,
                         const int* __restrict__ aoff, const int* __restrict__ tile_e,
                         const int* __restrict__ row_pk, const float* __restrict__ wt_pk,
                         unsigned short* __restrict__ Hout, float* __restrict__ Y) {
    __shared__ __align__(16) __bf16 As[128 * 32];
    __shared__ __align__(16) __bf16 Bs[128 * 32];
    const int t = blockIdx.y;
    if (t * 128 >= aoff[4]) return;
    const int e = tile_e[t];
    const int nb = blockIdx.x;
    const int tid = threadIdx.x;
    const int lane = tid & 63;
    const int wave = tid >> 6;
    const int wm = wave & 1, wn = wave >> 1;
    const int lm = lane & 15, q = lane >> 4;

    // staging: thread stages rows (tid>>2) and 64+(tid>>2); chunk slot tid&3;
    // global chunk xor-swizzled by row&3 (invariant under +64)
    const int srow = tid >> 2;
    const int schunk = ((tid & 3) ^ (srow & 3)) * 8;
    const __bf16* Ag0 = A + (size_t)(t * 128 + srow) * K + schunk;
    const __bf16* Ag1 = Ag0 + (size_t)64 * K;
    const __bf16* Bg0 = W + (size_t)e * N * K + (size_t)(nb * 128 + srow) * K + schunk;
    const __bf16* Bg1 = Bg0 + (size_t)64 * K;
    __bf16* Al0 = As + tid * 8;
    __bf16* Al1 = As + 64 * 32 + tid * 8;
    __bf16* Bl0 = Bs + tid * 8;
    __bf16* Bl1 = Bs + 64 * 32 + tid * 8;

    f32x4 acc[4][4] = {};
    const int sw = (q ^ (lm & 3)) * 8;
    int aof[4], bof[4];
#pragma unroll
    for (int i = 0; i < 4; ++i) {
        aof[i] = (wm * 64 + i * 16 + lm) * 32 + sw;
        bof[i] = (wn * 64 + i * 16 + lm) * 32 + sw;
    }

    for (int kt = 0; kt < K / 32; ++kt) {
        load_lds16(Ag0 + kt * 32, Al0);
        load_lds16(Ag1 + kt * 32, Al1);
        load_lds16(Bg0 + kt * 32, Bl0);
        load_lds16(Bg1 + kt * 32, Bl1);
        __syncthreads();
        bf16x8 af[4], bfr[4];
#pragma unroll
        for (int i = 0; i < 4; ++i) af[i] = *(const bf16x8*)(As + aof[i]);
#pragma unroll
        for (int j = 0; j < 4; ++j) bfr[j] = *(const bf16x8*)(Bs + bof[j]);
#pragma unroll
        for (int i = 0; i < 4; ++i)
#pragma unroll
            for (int j = 0; j < 4; ++j)
                acc[i][j] = __builtin_amdgcn_mfma_f32_16x16x32_bf16(af[i], bfr[j], acc[i][j], 0, 0, 0);
        __syncthreads();
    }

    if (MODE == 1) {
#pragma unroll
        for (int j = 0; j < 4; ++j) {
            int col = nb * 128 + wn * 64 + j * 16 + lm;
            float bv = bias[e * N + col];
#pragma unroll
            for (int i = 0; i < 4; ++i) {
                int rl = wm * 64 + i * 16 + q * 4;
                size_t base = (size_t)(t * 128 + rl) * N + col;
#pragma unroll
                for (int r = 0; r < 4; ++r) {
                    float v = acc[i][j][r] + bv;
                    v = 0.5f * v * (1.0f + erff(v * 0.70710678118f));
                    Hout[base + (size_t)r * N] = f2bf(v);
                }
            }
        }
    } else {
        float bv[4];
#pragma unroll
        for (int j = 0; j < 4; ++j) bv[j] = bias[e * N + nb * 128 + wn * 64 + j * 16 + lm];
#pragma unroll
        for (int i = 0; i < 4; ++i) {
#pragma unroll
            for (int r = 0; r < 4; ++r) {
                int ig = t * 128 + wm * 64 + i * 16 + q * 4 + r;
                int brow = row_pk[ig];
                if (brow >= 0) {
                    float wgt = wt_pk[ig];
#pragma unroll
                    for (int j = 0; j < 4; ++j) {
                        int col = nb * 128 + wn * 64 + j * 16 + lm;
                        atomicAdd(Y + (size_t)brow * DD + col, (acc[i][j][r] + bv[j]) * wgt);
                    }
                }
            }
        }
    }
}

// ---------------- launch ----------------
extern "C" void kernel_launch(void* const* d_in, const int* in_sizes, int n_in,
                              void* d_out, int out_size, void* d_ws, size_t ws_size,
                              hipStream_t stream) {
    const float* x   = (const float*)d_in[0];
    const float* gw  = (const float*)d_in[1];
    const float* gb  = (const float*)d_in[2];
    const float* lnw = (const float*)d_in[3];
    const float* lnb = (const float*)d_in[4];
    const float* w1  = (const float*)d_in[5];
    const float* b1  = (const float*)d_in[6];
    const float* w2  = (const float*)d_in[7];
    const float* b2  = (const float*)d_in[8];
    float* out = (float*)d_out;

    char* ws = (char*)d_ws;
    size_t o = 0;
    auto alloc = [&](size_t bytes) { size_t r = o; o += (bytes + 255) & ~(size_t)255; return r; };
    float* mu       = (float*)(ws + alloc((size_t)BB * 4));
    float* rstd     = (float*)(ws + alloc((size_t)BB * 4));
    int*   cnt      = (int*)(ws + alloc(16));
    int*   aoff     = (int*)(ws + alloc(5 * 4));
    int*   te       = (int*)(ws + alloc(NT * 4));
    int*   rows_tmp = (int*)(ws + alloc((size_t)EE * BB * 4));
    float* wts_tmp  = (float*)(ws + alloc((size_t)EE * BB * 4));
    int*   row_pk   = (int*)(ws + alloc((size_t)CAP * 4));
    float* wt_pk    = (float*)(ws + alloc((size_t)CAP * 4));
    unsigned short* w1t = (unsigned short*)(ws + alloc((size_t)EE * DD * HH * 2));
    unsigned short* w2t = (unsigned short*)(ws + alloc((size_t)EE * DD * HH * 2));
    unsigned short* Apk = (unsigned short*)(ws + alloc((size_t)CAP * DD * 2));
    unsigned short* Hpk = (unsigned short*)(ws + alloc((size_t)CAP * HH * 2));
    if (o > ws_size) return;  // workspace insufficient: fail loudly

    float* y_out     = out;
    float* probs_out = out + (size_t)BB * DD;
    float* idx_out   = probs_out + (size_t)BB * EE;
    float* w_out     = idx_out + (size_t)BB * 2;
    float* aux_out   = w_out + (size_t)BB * 2;

    hipMemsetAsync(y_out, 0, (size_t)BB * DD * 4, stream);
    hipMemsetAsync(cnt, 0, 16, stream);

    k_prep<DD, HH><<<dim3(HH / 64, DD / 64, EE), 256, 0, stream>>>(w1, w1t);
    k_prep<HH, DD><<<dim3(DD / 64, HH / 64, EE), 256, 0, stream>>>(w2, w2t);
    k_gate<<<BB, 256, 0, stream>>>(x, gw, gb, mu, rstd, cnt, rows_tmp, wts_tmp,
                                   probs_out, idx_out, w_out);
    k_aux<<<1, 256, 0, stream>>>(probs_out, cnt, aoff, te, aux_out);
    k_pack<<<CAP, 256, 0, stream>>>(x, lnw, lnb, mu, rstd, cnt, aoff, te,
                                    rows_tmp, wts_tmp, row_pk, wt_pk, Apk);
    moe_gemm<DD, HH, 1><<<dim3(HH / 128, NT), 256, 0, stream>>>(
        (const __bf16*)Apk, (const __bf16*)w1t, b1, aoff, te, nullptr, nullptr, Hpk, nullptr);
    moe_gemm<HH, DD, 2><<<dim3(DD / 128, NT), 256, 0, stream>>>(
        (const __bf16*)Hpk, (const __bf16*)w2t, b2, aoff, te, row_pk, wt_pk, nullptr, y_out);
}

// Round 3
// 886.809 us; speedup vs baseline: 1.0234x; 1.0234x over previous
//
#include <hip/hip_runtime.h>
#include <hip/hip_bf16.h>
#include <math.h>

// ---------------- constants ----------------
#define BB 8192
#define DD 1024
#define HH 4096
#define EE 4
#define NT 132              // row tiles of 128 covering B*k + per-expert pad
#define CAP (NT * 128)      // 16896 packed-row capacity

typedef __attribute__((ext_vector_type(8))) __bf16 bf16x8;
typedef __attribute__((ext_vector_type(4))) float f32x4;

__device__ __forceinline__ unsigned short f2bf(float f) {
    union { float f; unsigned u; } c; c.f = f;
    unsigned u = c.u;
    unsigned r = (u + 0x7FFFu + ((u >> 16) & 1u)) >> 16;
    return (unsigned short)r;
}

__device__ __forceinline__ void load_lds16(const void* g, void* l) {
    __builtin_amdgcn_global_load_lds(
        (const __attribute__((address_space(1))) void*)g,
        (__attribute__((address_space(3))) void*)l, 16, 0, 0);
}

// ---------------- weight transpose + bf16 convert ----------------
// src fp32 [E][R][C]  ->  dst bf16 [E][C][R]
template <int R, int C>
__global__ void k_prep(const float* __restrict__ src, unsigned short* __restrict__ dst) {
    __shared__ unsigned short tileT[64 * 72];   // [c][r], pad 72
    const int e = blockIdx.z;
    const int r0 = blockIdx.y * 64, c0 = blockIdx.x * 64;
    const float* s = src + (size_t)e * R * C;
    unsigned short* d = dst + (size_t)e * R * C;
    const int tid = threadIdx.x;
    const int cc = (tid & 15) * 4;
#pragma unroll
    for (int it = 0; it < 4; ++it) {
        int rr = (tid >> 4) + it * 16;
        float4 v = *(const float4*)(s + (size_t)(r0 + rr) * C + c0 + cc);
        tileT[(cc + 0) * 72 + rr] = f2bf(v.x);
        tileT[(cc + 1) * 72 + rr] = f2bf(v.y);
        tileT[(cc + 2) * 72 + rr] = f2bf(v.z);
        tileT[(cc + 3) * 72 + rr] = f2bf(v.w);
    }
    __syncthreads();
#pragma unroll
    for (int it = 0; it < 2; ++it) {
        int chunk = tid + it * 256;
        int cl = chunk >> 3, rl = (chunk & 7) * 8;
        uint4 vv = *(const uint4*)&tileT[cl * 72 + rl];
        *(uint4*)(d + (size_t)(c0 + cl) * R + r0 + rl) = vv;
    }
}

// ---------------- gating: logits, softmax, top2, LN stats, routing ----------------
__global__ void k_gate(const float* __restrict__ x, const float* __restrict__ gw,
                       const float* __restrict__ gb,
                       float* __restrict__ mu, float* __restrict__ rstd,
                       int* __restrict__ cnt, int* __restrict__ rows_tmp,
                       float* __restrict__ wts_tmp,
                       float* __restrict__ probs_out, float* __restrict__ idx_out,
                       float* __restrict__ w_out) {
    const int r = blockIdx.x, tid = threadIdx.x;
    float4 xv = *(const float4*)(x + (size_t)r * DD + tid * 4);
    float l[4], s, ss;
    s = xv.x + xv.y + xv.z + xv.w;
    ss = xv.x * xv.x + xv.y * xv.y + xv.z * xv.z + xv.w * xv.w;
#pragma unroll
    for (int e = 0; e < 4; ++e) {
        float4 g = *(const float4*)(gw + (size_t)e * DD + tid * 4);
        l[e] = xv.x * g.x + xv.y * g.y + xv.z * g.z + xv.w * g.w;
    }
    __shared__ float red[6][256];
    red[0][tid] = l[0]; red[1][tid] = l[1]; red[2][tid] = l[2]; red[3][tid] = l[3];
    red[4][tid] = s; red[5][tid] = ss;
    __syncthreads();
    for (int off = 128; off > 0; off >>= 1) {
        if (tid < off) {
#pragma unroll
            for (int q = 0; q < 6; ++q) red[q][tid] += red[q][tid + off];
        }
        __syncthreads();
    }
    if (tid == 0) {
        float sum = red[4][0], sumsq = red[5][0];
        float m = sum * (1.0f / DD);
        float var = sumsq * (1.0f / DD) - m * m;
        mu[r] = m;
        rstd[r] = rsqrtf(var + 1e-5f);
        float lg[4];
#pragma unroll
        for (int e = 0; e < 4; ++e) lg[e] = red[e][0] + gb[e];
        float mx = fmaxf(fmaxf(lg[0], lg[1]), fmaxf(lg[2], lg[3]));
        float p[4], tot = 0.f;
#pragma unroll
        for (int e = 0; e < 4; ++e) { p[e] = expf(lg[e] - mx); tot += p[e]; }
        float inv = 1.0f / tot;
#pragma unroll
        for (int e = 0; e < 4; ++e) { p[e] *= inv; probs_out[(size_t)r * 4 + e] = p[e]; }
        int e0 = 0; float p0 = p[0];
#pragma unroll
        for (int e = 1; e < 4; ++e) if (p[e] > p0) { p0 = p[e]; e0 = e; }
        int e1 = -1; float p1 = -1.f;
#pragma unroll
        for (int e = 0; e < 4; ++e) if (e != e0 && p[e] > p1) { p1 = p[e]; e1 = e; }
        float s2 = 1.0f / (p0 + p1 + 1e-9f);
        float w0 = p0 * s2, w1v = p1 * s2;
        idx_out[r * 2 + 0] = (float)e0;
        idx_out[r * 2 + 1] = (float)e1;
        w_out[r * 2 + 0] = w0;
        w_out[r * 2 + 1] = w1v;
        int pos0 = atomicAdd(cnt + e0, 1);
        rows_tmp[e0 * BB + pos0] = r; wts_tmp[e0 * BB + pos0] = w0;
        int pos1 = atomicAdd(cnt + e1, 1);
        rows_tmp[e1 * BB + pos1] = r; wts_tmp[e1 * BB + pos1] = w1v;
    }
}

// ---------------- aux loss + aligned offsets + tile table ----------------
__global__ void k_aux(const float* __restrict__ probs, const int* __restrict__ cnt,
                      int* __restrict__ aoff, int* __restrict__ tile_e,
                      float* __restrict__ aux_out) {
    const int tid = threadIdx.x;
    float s0 = 0, s1 = 0, s2 = 0, s3 = 0;
    for (int r = tid; r < BB; r += 256) {
        float4 p = *(const float4*)(probs + (size_t)r * 4);
        s0 += p.x; s1 += p.y; s2 += p.z; s3 += p.w;
    }
    __shared__ float red[4][256];
    red[0][tid] = s0; red[1][tid] = s1; red[2][tid] = s2; red[3][tid] = s3;
    __syncthreads();
    for (int off = 128; off > 0; off >>= 1) {
        if (tid < off) {
#pragma unroll
            for (int q = 0; q < 4; ++q) red[q][tid] += red[q][tid + off];
        }
        __syncthreads();
    }
    if (tid == 0) {
        float aux = 0.f;
        for (int e = 0; e < 4; ++e) {
            float mean_p = red[e][0] * (1.0f / BB);
            float frac = (float)cnt[e] * (1.0f / (BB * 2));
            aux += frac * mean_p;
        }
        aux_out[0] = 4.0f * aux;
        int a = 0; aoff[0] = 0;
        for (int e = 0; e < 4; ++e) { a += ((cnt[e] + 127) >> 7) << 7; aoff[e + 1] = a; }
        for (int t = 0; t < NT; ++t) {
            int ee = 0;
            for (int e = 0; e < 4; ++e)
                if (t * 128 >= aoff[e] && t * 128 < aoff[e + 1]) ee = e;
            tile_e[t] = ee;
        }
    }
}

// ---------------- pack: gather rows, LN + per-expert affine, bf16 ----------------
__global__ void k_pack(const float* __restrict__ x, const float* __restrict__ lnw,
                       const float* __restrict__ lnb,
                       const float* __restrict__ mu, const float* __restrict__ rstd,
                       const int* __restrict__ cnt, const int* __restrict__ aoff,
                       const int* __restrict__ tile_e,
                       const int* __restrict__ rows_tmp, const float* __restrict__ wts_tmp,
                       int* __restrict__ row_pk, float* __restrict__ wt_pk,
                       unsigned short* __restrict__ Apk) {
    const int i = blockIdx.x;
    if (i >= aoff[4]) return;
    const int e = tile_e[i >> 7];
    const int j = i - aoff[e];
    const int tid = threadIdx.x;
    unsigned short* dst = Apk + (size_t)i * DD + tid * 4;
    if (j < cnt[e]) {
        int b = rows_tmp[e * BB + j];
        if (tid == 0) { row_pk[i] = b; wt_pk[i] = wts_tmp[e * BB + j]; }
        float m = mu[b], rs = rstd[b];
        float4 xv = *(const float4*)(x + (size_t)b * DD + tid * 4);
        float4 wv = *(const float4*)(lnw + (size_t)e * DD + tid * 4);
        float4 bv = *(const float4*)(lnb + (size_t)e * DD + tid * 4);
        ushort4 o;
        o.x = f2bf((xv.x - m) * rs * wv.x + bv.x);
        o.y = f2bf((xv.y - m) * rs * wv.y + bv.y);
        o.z = f2bf((xv.z - m) * rs * wv.z + bv.z);
        o.w = f2bf((xv.w - m) * rs * wv.w + bv.w);
        *(ushort4*)dst = o;
    } else {
        if (tid == 0) { row_pk[i] = -1; wt_pk[i] = 0.f; }
        ushort4 z; z.x = z.y = z.z = z.w = 0;
        *(ushort4*)dst = z;
    }
}

// ---------------- grouped GEMM (m97 recipe, BK=64, t-fastest grid) ----------------
// grid = dim3(NT, N/128): blockIdx.x = row tile t, blockIdx.y = n tile.
// t-fastest linear order -> blocks sharing an A row-tile cluster onto few XCDs
// (L2 A-reuse); B n-tiles build small per-XCD resident sets.
// MODE 1: H = gelu(A @ W^T + b1) -> bf16 Hout     (K=1024, N=4096)
// MODE 2: y[row] += wt * (A @ W^T + b2)           (K=4096, N=1024)
template <int K, int N, int MODE>
__global__ void moe_gemm(const __bf16* __restrict__ A, const __bf16* __restrict__ W,
                         const float* __restrict__ bias,
                         const int* __restrict__ aoff, const int* __restrict__ tile_e,
                         const int* __restrict__ row_pk, const float* __restrict__ wt_pk,
                         unsigned short* __restrict__ Hout, float* __restrict__ Y) {
    __shared__ __align__(16) __bf16 As[128 * 64];
    __shared__ __align__(16) __bf16 Bs[128 * 64];
    const int t = blockIdx.x;
    if (t * 128 >= aoff[4]) return;
    const int e = tile_e[t];
    const int nb = blockIdx.y;
    const int tid = threadIdx.x;
    const int lane = tid & 63;
    const int wave = tid >> 6;
    const int wm = wave & 1, wn = wave >> 1;
    const int lm = lane & 15, q = lane >> 4;

    // staging (BK=64): 4 issues each for A and B; issue i covers rows
    // [i*32, i*32+32), thread -> row i*32+(tid>>3), k-chunk slot tid&7,
    // xor-swizzled by row&7 ((i*32)&7 == 0 so swizzle is issue-invariant).
    const int srow = tid >> 3;
    const int schunk = ((tid & 7) ^ (srow & 7)) * 8;
    const __bf16* Ag = A + (size_t)(t * 128 + srow) * K + schunk;
    const __bf16* Bg = W + (size_t)e * N * K + (size_t)(nb * 128 + srow) * K + schunk;
    __bf16* Al = As + tid * 8;
    __bf16* Bl = Bs + tid * 8;

    f32x4 acc[4][4] = {};
    // fragment LDS addr: row*64 + ((kslot ^ (row&7))*8), kslot = kk*4 + q
    int arow[4], brow[4];
#pragma unroll
    for (int i = 0; i < 4; ++i) {
        arow[i] = wm * 64 + i * 16 + lm;
        brow[i] = wn * 64 + i * 16 + lm;
    }

    for (int kt = 0; kt < K / 64; ++kt) {
#pragma unroll
        for (int i = 0; i < 4; ++i) load_lds16(Ag + (size_t)i * 32 * K + kt * 64, Al + i * 2048);
#pragma unroll
        for (int i = 0; i < 4; ++i) load_lds16(Bg + (size_t)i * 32 * K + kt * 64, Bl + i * 2048);
        __syncthreads();
#pragma unroll
        for (int kk = 0; kk < 2; ++kk) {
            bf16x8 af[4], bfr[4];
#pragma unroll
            for (int i = 0; i < 4; ++i)
                af[i] = *(const bf16x8*)(As + arow[i] * 64 + (((kk * 4 + q) ^ (arow[i] & 7)) * 8));
#pragma unroll
            for (int j = 0; j < 4; ++j)
                bfr[j] = *(const bf16x8*)(Bs + brow[j] * 64 + (((kk * 4 + q) ^ (brow[j] & 7)) * 8));
#pragma unroll
            for (int i = 0; i < 4; ++i)
#pragma unroll
                for (int j = 0; j < 4; ++j)
                    acc[i][j] = __builtin_amdgcn_mfma_f32_16x16x32_bf16(af[i], bfr[j], acc[i][j], 0, 0, 0);
        }
        __syncthreads();
    }

    if (MODE == 1) {
#pragma unroll
        for (int j = 0; j < 4; ++j) {
            int col = nb * 128 + wn * 64 + j * 16 + lm;
            float bv = bias[e * N + col];
#pragma unroll
            for (int i = 0; i < 4; ++i) {
                int rl = wm * 64 + i * 16 + q * 4;
                size_t base = (size_t)(t * 128 + rl) * N + col;
#pragma unroll
                for (int r = 0; r < 4; ++r) {
                    float v = acc[i][j][r] + bv;
                    v = 0.5f * v * (1.0f + erff(v * 0.70710678118f));
                    Hout[base + (size_t)r * N] = f2bf(v);
                }
            }
        }
    } else {
        float bv[4];
#pragma unroll
        for (int j = 0; j < 4; ++j) bv[j] = bias[e * N + nb * 128 + wn * 64 + j * 16 + lm];
#pragma unroll
        for (int i = 0; i < 4; ++i) {
#pragma unroll
            for (int r = 0; r < 4; ++r) {
                int ig = t * 128 + wm * 64 + i * 16 + q * 4 + r;
                int brw = row_pk[ig];
                if (brw >= 0) {
                    float wgt = wt_pk[ig];
#pragma unroll
                    for (int j = 0; j < 4; ++j) {
                        int col = nb * 128 + wn * 64 + j * 16 + lm;
                        atomicAdd(Y + (size_t)brw * DD + col, (acc[i][j][r] + bv[j]) * wgt);
                    }
                }
            }
        }
    }
}

// ---------------- launch ----------------
extern "C" void kernel_launch(void* const* d_in, const int* in_sizes, int n_in,
                              void* d_out, int out_size, void* d_ws, size_t ws_size,
                              hipStream_t stream) {
    const float* x   = (const float*)d_in[0];
    const float* gw  = (const float*)d_in[1];
    const float* gb  = (const float*)d_in[2];
    const float* lnw = (const float*)d_in[3];
    const float* lnb = (const float*)d_in[4];
    const float* w1  = (const float*)d_in[5];
    const float* b1  = (const float*)d_in[6];
    const float* w2  = (const float*)d_in[7];
    const float* b2  = (const float*)d_in[8];
    float* out = (float*)d_out;

    char* ws = (char*)d_ws;
    size_t o = 0;
    auto alloc = [&](size_t bytes) { size_t r = o; o += (bytes + 255) & ~(size_t)255; return r; };
    float* mu       = (float*)(ws + alloc((size_t)BB * 4));
    float* rstd     = (float*)(ws + alloc((size_t)BB * 4));
    int*   cnt      = (int*)(ws + alloc(16));
    int*   aoff     = (int*)(ws + alloc(5 * 4));
    int*   te       = (int*)(ws + alloc(NT * 4));
    int*   rows_tmp = (int*)(ws + alloc((size_t)EE * BB * 4));
    float* wts_tmp  = (float*)(ws + alloc((size_t)EE * BB * 4));
    int*   row_pk   = (int*)(ws + alloc((size_t)CAP * 4));
    float* wt_pk    = (float*)(ws + alloc((size_t)CAP * 4));
    unsigned short* w1t = (unsigned short*)(ws + alloc((size_t)EE * DD * HH * 2));
    unsigned short* w2t = (unsigned short*)(ws + alloc((size_t)EE * DD * HH * 2));
    unsigned short* Apk = (unsigned short*)(ws + alloc((size_t)CAP * DD * 2));
    unsigned short* Hpk = (unsigned short*)(ws + alloc((size_t)CAP * HH * 2));
    if (o > ws_size) return;  // workspace insufficient: fail loudly

    float* y_out     = out;
    float* probs_out = out + (size_t)BB * DD;
    float* idx_out   = probs_out + (size_t)BB * EE;
    float* w_out     = idx_out + (size_t)BB * 2;
    float* aux_out   = w_out + (size_t)BB * 2;

    hipMemsetAsync(y_out, 0, (size_t)BB * DD * 4, stream);
    hipMemsetAsync(cnt, 0, 16, stream);

    k_prep<DD, HH><<<dim3(HH / 64, DD / 64, EE), 256, 0, stream>>>(w1, w1t);
    k_prep<HH, DD><<<dim3(DD / 64, HH / 64, EE), 256, 0, stream>>>(w2, w2t);
    k_gate<<<BB, 256, 0, stream>>>(x, gw, gb, mu, rstd, cnt, rows_tmp, wts_tmp,
                                   probs_out, idx_out, w_out);
    k_aux<<<1, 256, 0, stream>>>(probs_out, cnt, aoff, te, aux_out);
    k_pack<<<CAP, 256, 0, stream>>>(x, lnw, lnb, mu, rstd, cnt, aoff, te,
                                    rows_tmp, wts_tmp, row_pk, wt_pk, Apk);
    moe_gemm<DD, HH, 1><<<dim3(NT, HH / 128), 256, 0, stream>>>(
        (const __bf16*)Apk, (const __bf16*)w1t, b1, aoff, te, nullptr, nullptr, Hpk, nullptr);
    moe_gemm<HH, DD, 2><<<dim3(NT, DD / 128), 256, 0, stream>>>(
        (const __bf16*)Hpk, (const __bf16*)w2t, b2, aoff, te, row_pk, wt_pk, nullptr, y_out);
}

// Round 4
// 627.759 us; speedup vs baseline: 1.4457x; 1.4127x over previous
//
#include <hip/hip_runtime.h>
#include <hip/hip_bf16.h>
#include <math.h>

// ---------------- constants ----------------
#define BB 8192
#define DD 1024
#define HH 4096
#define EE 4
#define NT 132              // row tiles of 128 covering B*k + per-expert pad
#define CAP (NT * 128)      // 16896 packed-row capacity

typedef __attribute__((ext_vector_type(8))) __bf16 bf16x8;
typedef __attribute__((ext_vector_type(4))) float f32x4;

__device__ __forceinline__ unsigned short f2bf(float f) {
    union { float f; unsigned u; } c; c.f = f;
    unsigned u = c.u;
    unsigned r = (u + 0x7FFFu + ((u >> 16) & 1u)) >> 16;
    return (unsigned short)r;
}

__device__ __forceinline__ void load_lds16(const void* g, void* l) {
    __builtin_amdgcn_global_load_lds(
        (const __attribute__((address_space(1))) void*)g,
        (__attribute__((address_space(3))) void*)l, 16, 0, 0);
}

// ---------------- weight transpose + bf16 convert ----------------
// src fp32 [E][R][C]  ->  dst bf16 [E][C][R]
template <int R, int C>
__global__ void k_prep(const float* __restrict__ src, unsigned short* __restrict__ dst) {
    __shared__ unsigned short tileT[64 * 72];   // [c][r], pad 72
    const int e = blockIdx.z;
    const int r0 = blockIdx.y * 64, c0 = blockIdx.x * 64;
    const float* s = src + (size_t)e * R * C;
    unsigned short* d = dst + (size_t)e * R * C;
    const int tid = threadIdx.x;
    const int cc = (tid & 15) * 4;
#pragma unroll
    for (int it = 0; it < 4; ++it) {
        int rr = (tid >> 4) + it * 16;
        float4 v = *(const float4*)(s + (size_t)(r0 + rr) * C + c0 + cc);
        tileT[(cc + 0) * 72 + rr] = f2bf(v.x);
        tileT[(cc + 1) * 72 + rr] = f2bf(v.y);
        tileT[(cc + 2) * 72 + rr] = f2bf(v.z);
        tileT[(cc + 3) * 72 + rr] = f2bf(v.w);
    }
    __syncthreads();
#pragma unroll
    for (int it = 0; it < 2; ++it) {
        int chunk = tid + it * 256;
        int cl = chunk >> 3, rl = (chunk & 7) * 8;
        uint4 vv = *(const uint4*)&tileT[cl * 72 + rl];
        *(uint4*)(d + (size_t)(c0 + cl) * R + r0 + rl) = vv;
    }
}

// ---------------- gating: wave-per-row, block-aggregated routing ----------------
// grid 256 blocks x 32 rows; 4 waves/block, each wave does 8 rows.
__global__ __launch_bounds__(256) void k_gate(
        const float* __restrict__ x, const float* __restrict__ gw,
        const float* __restrict__ gb,
        float* __restrict__ mu, float* __restrict__ rstd,
        int* __restrict__ cnt, int* __restrict__ rows_tmp,
        float* __restrict__ wts_tmp,
        float* __restrict__ probs_out, float* __restrict__ idx_out,
        float* __restrict__ w_out) {
    const int tid = threadIdx.x;
    const int lane = tid & 63, wv = tid >> 6;
    __shared__ int   s_e[64];
    __shared__ float s_w[64];
    __shared__ int   s_pos[64];
    __shared__ int   s_base[4];

    for (int i = 0; i < 8; ++i) {
        const int rloc = wv * 8 + i;
        const int r = blockIdx.x * 32 + rloc;
        float l0 = 0, l1 = 0, l2 = 0, l3 = 0, s = 0, ss = 0;
#pragma unroll
        for (int k = 0; k < 4; ++k) {
            const int off = k * 256 + lane * 4;
            float4 xv = *(const float4*)(x + (size_t)r * DD + off);
            s  += xv.x + xv.y + xv.z + xv.w;
            ss += xv.x * xv.x + xv.y * xv.y + xv.z * xv.z + xv.w * xv.w;
            float4 g0 = *(const float4*)(gw + 0 * DD + off);
            float4 g1 = *(const float4*)(gw + 1 * DD + off);
            float4 g2 = *(const float4*)(gw + 2 * DD + off);
            float4 g3 = *(const float4*)(gw + 3 * DD + off);
            l0 += xv.x * g0.x + xv.y * g0.y + xv.z * g0.z + xv.w * g0.w;
            l1 += xv.x * g1.x + xv.y * g1.y + xv.z * g1.z + xv.w * g1.w;
            l2 += xv.x * g2.x + xv.y * g2.y + xv.z * g2.z + xv.w * g2.w;
            l3 += xv.x * g3.x + xv.y * g3.y + xv.z * g3.z + xv.w * g3.w;
        }
#pragma unroll
        for (int off = 32; off > 0; off >>= 1) {
            l0 += __shfl_xor(l0, off, 64);
            l1 += __shfl_xor(l1, off, 64);
            l2 += __shfl_xor(l2, off, 64);
            l3 += __shfl_xor(l3, off, 64);
            s  += __shfl_xor(s,  off, 64);
            ss += __shfl_xor(ss, off, 64);
        }
        if (lane == 0) {
            float m = s * (1.0f / DD);
            float var = ss * (1.0f / DD) - m * m;
            mu[r] = m;
            rstd[r] = rsqrtf(var + 1e-5f);
            float lg[4] = { l0 + gb[0], l1 + gb[1], l2 + gb[2], l3 + gb[3] };
            float mx = fmaxf(fmaxf(lg[0], lg[1]), fmaxf(lg[2], lg[3]));
            float p[4], tot = 0.f;
#pragma unroll
            for (int e = 0; e < 4; ++e) { p[e] = __expf(lg[e] - mx); tot += p[e]; }
            float inv = 1.0f / tot;
#pragma unroll
            for (int e = 0; e < 4; ++e) { p[e] *= inv; probs_out[(size_t)r * 4 + e] = p[e]; }
            int e0 = 0; float p0 = p[0];
#pragma unroll
            for (int e = 1; e < 4; ++e) if (p[e] > p0) { p0 = p[e]; e0 = e; }
            int e1 = -1; float p1 = -1.f;
#pragma unroll
            for (int e = 0; e < 4; ++e) if (e != e0 && p[e] > p1) { p1 = p[e]; e1 = e; }
            float s2 = 1.0f / (p0 + p1 + 1e-9f);
            float w0 = p0 * s2, w1v = p1 * s2;
            idx_out[r * 2 + 0] = (float)e0;
            idx_out[r * 2 + 1] = (float)e1;
            w_out[r * 2 + 0] = w0;
            w_out[r * 2 + 1] = w1v;
            s_e[rloc * 2 + 0] = e0; s_w[rloc * 2 + 0] = w0;
            s_e[rloc * 2 + 1] = e1; s_w[rloc * 2 + 1] = w1v;
        }
    }
    __syncthreads();
    if (tid < 4) {                      // block-local count + position assign
        int c = 0;
        for (int k = 0; k < 64; ++k)
            if (s_e[k] == tid) s_pos[k] = c++;
        s_base[tid] = atomicAdd(cnt + tid, c);
    }
    __syncthreads();
    if (tid < 64) {
        int e = s_e[tid];
        int p = s_base[e] + s_pos[tid];
        int r = blockIdx.x * 32 + (tid >> 1);
        rows_tmp[e * BB + p] = r;
        wts_tmp[e * BB + p] = s_w[tid];
    }
}

// ---------------- aux loss + aligned offsets + tile table ----------------
__global__ void k_aux(const float* __restrict__ probs, const int* __restrict__ cnt,
                      int* __restrict__ aoff, int* __restrict__ tile_e,
                      float* __restrict__ aux_out) {
    const int tid = threadIdx.x;
    float s0 = 0, s1 = 0, s2 = 0, s3 = 0;
    for (int r = tid; r < BB; r += 256) {
        float4 p = *(const float4*)(probs + (size_t)r * 4);
        s0 += p.x; s1 += p.y; s2 += p.z; s3 += p.w;
    }
    __shared__ float red[4][256];
    red[0][tid] = s0; red[1][tid] = s1; red[2][tid] = s2; red[3][tid] = s3;
    __syncthreads();
    for (int off = 128; off > 0; off >>= 1) {
        if (tid < off) {
#pragma unroll
            for (int q = 0; q < 4; ++q) red[q][tid] += red[q][tid + off];
        }
        __syncthreads();
    }
    if (tid == 0) {
        float aux = 0.f;
        for (int e = 0; e < 4; ++e) {
            float mean_p = red[e][0] * (1.0f / BB);
            float frac = (float)cnt[e] * (1.0f / (BB * 2));
            aux += frac * mean_p;
        }
        aux_out[0] = 4.0f * aux;
        int a = 0; aoff[0] = 0;
        for (int e = 0; e < 4; ++e) { a += ((cnt[e] + 127) >> 7) << 7; aoff[e + 1] = a; }
        for (int t = 0; t < NT; ++t) {
            int ee = 0;
            for (int e = 0; e < 4; ++e)
                if (t * 128 >= aoff[e] && t * 128 < aoff[e + 1]) ee = e;
            tile_e[t] = ee;
        }
    }
}

// ---------------- pack: gather rows, LN + per-expert affine, bf16 ----------------
__global__ void k_pack(const float* __restrict__ x, const float* __restrict__ lnw,
                       const float* __restrict__ lnb,
                       const float* __restrict__ mu, const float* __restrict__ rstd,
                       const int* __restrict__ cnt, const int* __restrict__ aoff,
                       const int* __restrict__ tile_e,
                       const int* __restrict__ rows_tmp, const float* __restrict__ wts_tmp,
                       int* __restrict__ row_pk, float* __restrict__ wt_pk,
                       unsigned short* __restrict__ Apk) {
    const int i = blockIdx.x;
    if (i >= aoff[4]) return;
    const int e = tile_e[i >> 7];
    const int j = i - aoff[e];
    const int tid = threadIdx.x;
    unsigned short* dst = Apk + (size_t)i * DD + tid * 4;
    if (j < cnt[e]) {
        int b = rows_tmp[e * BB + j];
        if (tid == 0) { row_pk[i] = b; wt_pk[i] = wts_tmp[e * BB + j]; }
        float m = mu[b], rs = rstd[b];
        float4 xv = *(const float4*)(x + (size_t)b * DD + tid * 4);
        float4 wv = *(const float4*)(lnw + (size_t)e * DD + tid * 4);
        float4 bv = *(const float4*)(lnb + (size_t)e * DD + tid * 4);
        ushort4 o;
        o.x = f2bf((xv.x - m) * rs * wv.x + bv.x);
        o.y = f2bf((xv.y - m) * rs * wv.y + bv.y);
        o.z = f2bf((xv.z - m) * rs * wv.z + bv.z);
        o.w = f2bf((xv.w - m) * rs * wv.w + bv.w);
        *(ushort4*)dst = o;
    } else {
        if (tid == 0) { row_pk[i] = -1; wt_pk[i] = 0.f; }
        ushort4 z; z.x = z.y = z.z = z.w = 0;
        *(ushort4*)dst = z;
    }
}

// ---------------- grouped GEMM (m97 recipe, BK=64, XCD-aware raster) ----------------
// 1-D grid. xcd = id&7 (HW round-robin); XCD pair (xcd>>1) owns a contiguous
// band of 33 row-tiles; xcd&1 picks an nb-half. Slot order: nbg -> tloc -> nbi
// so B groups stay L2-resident while the A band streams once per group.
// MODE 1: H = gelu(A @ W^T + b1) -> bf16 Hout     (K=1024, N=4096)
// MODE 2: y[row] += wt * (A @ W^T + b2)           (K=4096, N=1024)
template <int K, int N, int MODE>
__global__ void moe_gemm(const __bf16* __restrict__ A, const __bf16* __restrict__ W,
                         const float* __restrict__ bias,
                         const int* __restrict__ aoff, const int* __restrict__ tile_e,
                         const int* __restrict__ row_pk, const float* __restrict__ wt_pk,
                         unsigned short* __restrict__ Hout, float* __restrict__ Y) {
    __shared__ __align__(16) __bf16 As[128 * 64];
    __shared__ __align__(16) __bf16 Bs[128 * 64];

    constexpr int NBHALF = N / 128 / 2;                 // nb per XCD half
    constexpr int NBGRP  = (NBHALF >= 8) ? 8 : NBHALF;  // L2-resident B group
    const int id = blockIdx.x;
    const int xcd = id & 7, slot = id >> 3;
    const int nbg  = slot / (33 * NBGRP);
    const int rem  = slot - nbg * (33 * NBGRP);
    const int tloc = rem / NBGRP;
    const int nbi  = rem - tloc * NBGRP;
    const int t  = (xcd >> 1) * 33 + tloc;
    const int nb = (xcd & 1) * NBHALF + nbg * NBGRP + nbi;

    if (t * 128 >= aoff[4]) return;
    const int e = tile_e[t];
    const int tid = threadIdx.x;
    const int lane = tid & 63;
    const int wave = tid >> 6;
    const int wm = wave & 1, wn = wave >> 1;
    const int lm = lane & 15, q = lane >> 4;

    // staging (BK=64): 4 issues each for A and B; issue i covers rows
    // [i*32, i*32+32), thread -> row i*32+(tid>>3), k-chunk slot tid&7,
    // xor-swizzled by row&7 ((i*32)&7 == 0 so swizzle is issue-invariant).
    const int srow = tid >> 3;
    const int schunk = ((tid & 7) ^ (srow & 7)) * 8;
    const __bf16* Ag = A + (size_t)(t * 128 + srow) * K + schunk;
    const __bf16* Bg = W + (size_t)e * N * K + (size_t)(nb * 128 + srow) * K + schunk;
    __bf16* Al = As + tid * 8;
    __bf16* Bl = Bs + tid * 8;

    f32x4 acc[4][4] = {};
    int arow[4], brow[4];
#pragma unroll
    for (int i = 0; i < 4; ++i) {
        arow[i] = wm * 64 + i * 16 + lm;
        brow[i] = wn * 64 + i * 16 + lm;
    }

    for (int kt = 0; kt < K / 64; ++kt) {
#pragma unroll
        for (int i = 0; i < 4; ++i) load_lds16(Ag + (size_t)i * 32 * K + kt * 64, Al + i * 2048);
#pragma unroll
        for (int i = 0; i < 4; ++i) load_lds16(Bg + (size_t)i * 32 * K + kt * 64, Bl + i * 2048);
        __syncthreads();
#pragma unroll
        for (int kk = 0; kk < 2; ++kk) {
            bf16x8 af[4], bfr[4];
#pragma unroll
            for (int i = 0; i < 4; ++i)
                af[i] = *(const bf16x8*)(As + arow[i] * 64 + (((kk * 4 + q) ^ (arow[i] & 7)) * 8));
#pragma unroll
            for (int j = 0; j < 4; ++j)
                bfr[j] = *(const bf16x8*)(Bs + brow[j] * 64 + (((kk * 4 + q) ^ (brow[j] & 7)) * 8));
#pragma unroll
            for (int i = 0; i < 4; ++i)
#pragma unroll
                for (int j = 0; j < 4; ++j)
                    acc[i][j] = __builtin_amdgcn_mfma_f32_16x16x32_bf16(af[i], bfr[j], acc[i][j], 0, 0, 0);
        }
        __syncthreads();
    }

    if (MODE == 1) {
#pragma unroll
        for (int j = 0; j < 4; ++j) {
            int col = nb * 128 + wn * 64 + j * 16 + lm;
            float bv = bias[e * N + col];
#pragma unroll
            for (int i = 0; i < 4; ++i) {
                int rl = wm * 64 + i * 16 + q * 4;
                size_t base = (size_t)(t * 128 + rl) * N + col;
#pragma unroll
                for (int r = 0; r < 4; ++r) {
                    float v = acc[i][j][r] + bv;
                    // tanh-form GELU via sigmoid: v * sigmoid(2u)
                    float u2 = 2.0f * v * (0.7978845608f + 0.0356774081f * v * v);
                    float g = v / (1.0f + __expf(-u2));
                    Hout[base + (size_t)r * N] = f2bf(g);
                }
            }
        }
    } else {
        float bv[4];
#pragma unroll
        for (int j = 0; j < 4; ++j) bv[j] = bias[e * N + nb * 128 + wn * 64 + j * 16 + lm];
#pragma unroll
        for (int i = 0; i < 4; ++i) {
#pragma unroll
            for (int r = 0; r < 4; ++r) {
                int ig = t * 128 + wm * 64 + i * 16 + q * 4 + r;
                int brw = row_pk[ig];
                if (brw >= 0) {
                    float wgt = wt_pk[ig];
#pragma unroll
                    for (int j = 0; j < 4; ++j) {
                        int col = nb * 128 + wn * 64 + j * 16 + lm;
                        atomicAdd(Y + (size_t)brw * DD + col, (acc[i][j][r] + bv[j]) * wgt);
                    }
                }
            }
        }
    }
}

// ---------------- launch ----------------
extern "C" void kernel_launch(void* const* d_in, const int* in_sizes, int n_in,
                              void* d_out, int out_size, void* d_ws, size_t ws_size,
                              hipStream_t stream) {
    const float* x   = (const float*)d_in[0];
    const float* gw  = (const float*)d_in[1];
    const float* gb  = (const float*)d_in[2];
    const float* lnw = (const float*)d_in[3];
    const float* lnb = (const float*)d_in[4];
    const float* w1  = (const float*)d_in[5];
    const float* b1  = (const float*)d_in[6];
    const float* w2  = (const float*)d_in[7];
    const float* b2  = (const float*)d_in[8];
    float* out = (float*)d_out;

    char* ws = (char*)d_ws;
    size_t o = 0;
    auto alloc = [&](size_t bytes) { size_t r = o; o += (bytes + 255) & ~(size_t)255; return r; };
    float* mu       = (float*)(ws + alloc((size_t)BB * 4));
    float* rstd     = (float*)(ws + alloc((size_t)BB * 4));
    int*   cnt      = (int*)(ws + alloc(16));
    int*   aoff     = (int*)(ws + alloc(5 * 4));
    int*   te       = (int*)(ws + alloc(NT * 4));
    int*   rows_tmp = (int*)(ws + alloc((size_t)EE * BB * 4));
    float* wts_tmp  = (float*)(ws + alloc((size_t)EE * BB * 4));
    int*   row_pk   = (int*)(ws + alloc((size_t)CAP * 4));
    float* wt_pk    = (float*)(ws + alloc((size_t)CAP * 4));
    unsigned short* w1t = (unsigned short*)(ws + alloc((size_t)EE * DD * HH * 2));
    unsigned short* w2t = (unsigned short*)(ws + alloc((size_t)EE * DD * HH * 2));
    unsigned short* Apk = (unsigned short*)(ws + alloc((size_t)CAP * DD * 2));
    unsigned short* Hpk = (unsigned short*)(ws + alloc((size_t)CAP * HH * 2));
    if (o > ws_size) return;  // workspace insufficient: fail loudly

    float* y_out     = out;
    float* probs_out = out + (size_t)BB * DD;
    float* idx_out   = probs_out + (size_t)BB * EE;
    float* w_out     = idx_out + (size_t)BB * 2;
    float* aux_out   = w_out + (size_t)BB * 2;

    hipMemsetAsync(y_out, 0, (size_t)BB * DD * 4, stream);
    hipMemsetAsync(cnt, 0, 16, stream);

    k_prep<DD, HH><<<dim3(HH / 64, DD / 64, EE), 256, 0, stream>>>(w1, w1t);
    k_prep<HH, DD><<<dim3(DD / 64, HH / 64, EE), 256, 0, stream>>>(w2, w2t);
    k_gate<<<BB / 32, 256, 0, stream>>>(x, gw, gb, mu, rstd, cnt, rows_tmp, wts_tmp,
                                        probs_out, idx_out, w_out);
    k_aux<<<1, 256, 0, stream>>>(probs_out, cnt, aoff, te, aux_out);
    k_pack<<<CAP, 256, 0, stream>>>(x, lnw, lnb, mu, rstd, cnt, aoff, te,
                                    rows_tmp, wts_tmp, row_pk, wt_pk, Apk);
    moe_gemm<DD, HH, 1><<<8 * 33 * (HH / 256), 256, 0, stream>>>(
        (const __bf16*)Apk, (const __bf16*)w1t, b1, aoff, te, nullptr, nullptr, Hpk, nullptr);
    moe_gemm<HH, DD, 2><<<8 * 33 * (DD / 256), 256, 0, stream>>>(
        (const __bf16*)Hpk, (const __bf16*)w2t, b2, aoff, te, row_pk, wt_pk, nullptr, y_out);
}